// Round 3
// baseline (64.450 us; speedup 1.0000x reference)
//
#include <hip/hip_runtime.h>
#include <hip/hip_bf16.h>
#include <stdint.h>

// Problem constants (fixed by the reference)
#define B_SZ 8192
#define D_SZ 256
#define R_SZ 8
#define N_SZ 1024
#define C_SZ (B_SZ / R_SZ)          // 1024
#define CN   (C_SZ * N_SZ)          // 1048576
#define L_SZ (B_SZ + 2 * R_SZ * CN) // 16785408 (logits length)
#define BD   (B_SZ * D_SZ)          // elements per ws array

typedef short bf16x8 __attribute__((ext_vector_type(8)));
typedef float f32x4  __attribute__((ext_vector_type(4)));

static __device__ __forceinline__ unsigned short f2bf(float f) {
  unsigned u = __float_as_uint(f);
  u += 0x7FFFu + ((u >> 16) & 1u);   // RNE
  return (unsigned short)(u >> 16);
}
static __device__ __forceinline__ float bf2f(unsigned short h) {
  return __uint_as_float(((unsigned)h) << 16);
}
static __device__ __forceinline__ float sigmoidf_(float x) {
  return 1.0f / (1.0f + __expf(-x));
}
static __device__ __forceinline__ void gload16(const void* g, void* l) {
  __builtin_amdgcn_global_load_lds(
      (const __attribute__((address_space(1))) void*)g,
      (__attribute__((address_space(3))) void*)l, 16, 0, 0);
}

// ---------------------------------------------------------------------------
// Phase 1: F-reduce emb -> lhs/rhs, split into bf16 hi+lo in ws, pos logits.
// One wave per batch row i. 2048 blocks x 256 threads. (~8 us, BW-bound.)
// ---------------------------------------------------------------------------
__global__ __launch_bounds__(256) void prep_kernel(
    const float* __restrict__ emb, const float* __restrict__ trans,
    const int* __restrict__ rels, float* __restrict__ out,
    unsigned short* __restrict__ ws) {
  unsigned short* lhs_hi = ws;
  unsigned short* lhs_lo = ws + (size_t)BD;
  unsigned short* rhs_hi = ws + (size_t)2 * BD;
  unsigned short* rhs_lo = ws + (size_t)3 * BD;

  int wave = threadIdx.x >> 6;
  int lane = threadIdx.x & 63;
  int i = blockIdx.x * 4 + wave;            // 0..B-1

  const float4* emb4 = (const float4*)emb;  // emb row j = 128 float4 (F*D=512 f32)
  size_t bl = (size_t)(2 * i) * 128;
  size_t br = (size_t)(2 * i + 1) * 128;
  float4 a0 = emb4[bl + lane];
  float4 a1 = emb4[bl + 64 + lane];
  float4 b0 = emb4[br + lane];
  float4 b1 = emb4[br + 64 + lane];
  float lh[4] = {a0.x + a1.x, a0.y + a1.y, a0.z + a1.z, a0.w + a1.w};
  float rh[4] = {b0.x + b1.x, b0.y + b1.y, b0.z + b1.z, b0.w + b1.w};

  int rel = rels[i];
  float4 tv = ((const float4*)trans)[rel * 64 + lane];
  float tt[4] = {tv.x, tv.y, tv.z, tv.w};

  float p = 0.f;
#pragma unroll
  for (int j = 0; j < 4; ++j) p += lh[j] * (rh[j] + tt[j]);
#pragma unroll
  for (int off = 32; off; off >>= 1) p += __shfl_xor(p, off, 64);
  if (lane == 0) {
    out[i] = p;
    out[(size_t)L_SZ + i] = sigmoidf_(p);
  }

  unsigned short h[4], l[4];
#pragma unroll
  for (int j = 0; j < 4; ++j) {
    h[j] = f2bf(lh[j]);
    l[j] = f2bf(lh[j] - bf2f(h[j]));
  }
  *(ushort4*)(lhs_hi + (size_t)i * 256 + lane * 4) = make_ushort4(h[0], h[1], h[2], h[3]);
  *(ushort4*)(lhs_lo + (size_t)i * 256 + lane * 4) = make_ushort4(l[0], l[1], l[2], l[3]);
#pragma unroll
  for (int j = 0; j < 4; ++j) {
    h[j] = f2bf(rh[j]);
    l[j] = f2bf(rh[j] - bf2f(h[j]));
  }
  *(ushort4*)(rhs_hi + (size_t)i * 256 + lane * 4) = make_ushort4(h[0], h[1], h[2], h[3]);
  *(ushort4*)(rhs_lo + (size_t)i * 256 + lane * 4) = make_ushort4(l[0], l[1], l[2], l[3]);
}

// ---------------------------------------------------------------------------
// Phase 2: gather-GEMM negatives. 128x128 tile, 4 waves (2x2), 1024 blocks
// (= 2 blocks/CU), one-pass staging of Ah/Al/Bh/Bl per BK=32 slice (32 KB/buf,
// dbuf 64 KB). Shared-fragment split-bf16: acc += Ah*Bh + Al*Bh + Ah*Bl
// (48 MFMA + 16 ds_read_b128 per barrier-pair per wave). Counted-vmcnt
// pipeline: STAGE(next); vmcnt(8); bar; COMPUTE(cur); lgkm(0); bar.
// XOR source-swizzle (chunk ^ (row>>1)&3) with linear global_load_lds dest;
// same XOR on ds_read -> conflict-free. XCD swizzle: one relation r per XCD.
// ---------------------------------------------------------------------------
__global__ __launch_bounds__(256, 2) void negs_kernel(
    const unsigned short* __restrict__ ws,
    const int* __restrict__ order,
    const int* __restrict__ negL, const int* __restrict__ negR,
    float* __restrict__ out) {
  __shared__ char lds[2][32768];  // per buf: Ah@0 Al@8K Bh@16K Bl@24K

  const char* lhs_hi = (const char*)ws;
  const char* lhs_lo = (const char*)(ws + (size_t)BD);
  const char* rhs_hi = (const char*)(ws + (size_t)2 * BD);
  const char* rhs_lo = (const char*)(ws + (size_t)3 * BD);

  int hw = blockIdx.x;
  int bid = (hw & 7) * 128 + (hw >> 3);   // bijective: 1024 = 8 XCD x 128; r == XCD
  int ntile = bid & 7;
  int ctile = (bid >> 3) & 7;
  int side  = (bid >> 6) & 1;
  int r     = bid >> 7;

  int t = threadIdx.x;
  int wave = t >> 6, lane = t & 63;
  int wrow = wave >> 1, wcol = wave & 1;

  // side 0: negs_lhs = s_rhs . samp_lhs^T ; side 1: negs_rhs = s_lhs . samp_rhs^T
  const char* aHi = side ? lhs_hi : rhs_hi;
  const char* aLo = side ? lhs_lo : rhs_lo;
  const char* bHi = side ? rhs_hi : lhs_hi;
  const char* bLo = side ? rhs_lo : lhs_lo;
  const int* negp = side ? negR : negL;

  // Staging map: slot s in [0,512) per array -> row s>>2 (0..127), chunk s&3.
  // Thread t covers slots t and t+256 (rows t>>2 and 64+(t>>2)).
  // Source chunk inverse-swizzled by (row>>1)&3; same for row and row+64.
  unsigned srcswz = (unsigned)((((t & 3) ^ ((t >> 3) & 3))) << 4);
  int r0 = t >> 2;
  unsigned aoff0 = (unsigned)order[r * C_SZ + ctile * 128 + r0] * 512u + srcswz;
  unsigned aoff1 = (unsigned)order[r * C_SZ + ctile * 128 + 64 + r0] * 512u + srcswz;
  unsigned boff0 = (unsigned)negp[r * N_SZ + ntile * 128 + r0] * 512u + srcswz;
  unsigned boff1 = (unsigned)negp[r * N_SZ + ntile * 128 + 64 + r0] * 512u + srcswz;
  unsigned dst0 = (unsigned)t * 16u;          // slot t
  unsigned dst1 = 4096u + (unsigned)t * 16u;  // slot t+256

  auto STAGE = [&](int buf, int kt) {
    unsigned kb = (unsigned)kt * 64u;
    char* L = &lds[buf][0];
    gload16(aHi + aoff0 + kb, L + dst0);
    gload16(aHi + aoff1 + kb, L + dst1);
    gload16(aLo + aoff0 + kb, L + 8192 + dst0);
    gload16(aLo + aoff1 + kb, L + 8192 + dst1);
    gload16(bHi + boff0 + kb, L + 16384 + dst0);
    gload16(bHi + boff1 + kb, L + 16384 + dst1);
    gload16(bLo + boff0 + kb, L + 24576 + dst0);
    gload16(bLo + boff1 + kb, L + 24576 + dst1);
  };

  f32x4 acc[4][4] = {};
  int lx = lane & 15;
  int kch = (((lane >> 4) ^ ((lane >> 1) & 3)) << 4);  // swizzled 16B chunk in 64B row

  auto COMPUTE = [&](int buf) {
    const char* L = &lds[buf][0];
    bf16x8 ah[4], al_[4], bh[4], bl_[4];
#pragma unroll
    for (int mi = 0; mi < 4; ++mi) {
      int off = (wrow * 64 + mi * 16 + lx) * 64 + kch;
      ah[mi]  = *(const bf16x8*)(L + off);
      al_[mi] = *(const bf16x8*)(L + 8192 + off);
    }
#pragma unroll
    for (int ni = 0; ni < 4; ++ni) {
      int off = (wcol * 64 + ni * 16 + lx) * 64 + kch;
      bh[ni]  = *(const bf16x8*)(L + 16384 + off);
      bl_[ni] = *(const bf16x8*)(L + 24576 + off);
    }
#pragma unroll
    for (int mi = 0; mi < 4; ++mi)
#pragma unroll
      for (int ni = 0; ni < 4; ++ni) {
        acc[mi][ni] = __builtin_amdgcn_mfma_f32_16x16x32_bf16(ah[mi],  bh[ni],  acc[mi][ni], 0, 0, 0);
        acc[mi][ni] = __builtin_amdgcn_mfma_f32_16x16x32_bf16(al_[mi], bh[ni],  acc[mi][ni], 0, 0, 0);
        acc[mi][ni] = __builtin_amdgcn_mfma_f32_16x16x32_bf16(ah[mi],  bl_[ni], acc[mi][ni], 0, 0, 0);
      }
  };

  STAGE(0, 0);
#pragma unroll 1
  for (int kt = 0; kt < 8; ++kt) {
    if (kt < 7) {
      STAGE((kt + 1) & 1, kt + 1);
      asm volatile("s_waitcnt vmcnt(8)" ::: "memory");  // cur's 8 landed; next's 8 in flight
    } else {
      asm volatile("s_waitcnt vmcnt(0)" ::: "memory");
    }
    asm volatile("s_barrier" ::: "memory");
    COMPUTE(kt & 1);
    asm volatile("s_waitcnt lgkmcnt(0)\n\ts_barrier" ::: "memory");
  }

  // Epilogue: C/D layout col = lane&15 (n), row = (lane>>4)*4 + j (c).
  size_t obase = (size_t)B_SZ + ((size_t)(r * 2 + side)) * CN;
  int gcb = ntile * 128 + wcol * 64 + lx;
  int grb = ctile * 128 + wrow * 64 + ((lane >> 4) << 2);
#pragma unroll
  for (int mi = 0; mi < 4; ++mi) {
#pragma unroll
    for (int ni = 0; ni < 4; ++ni) {
      int gc = gcb + ni * 16;
#pragma unroll
      for (int j = 0; j < 4; ++j) {
        int gr = grb + mi * 16 + j;
        size_t idx = obase + (size_t)gr * N_SZ + gc;
        float v = acc[mi][ni][j];
        __builtin_nontemporal_store(v, &out[idx]);
        __builtin_nontemporal_store(sigmoidf_(v), &out[(size_t)L_SZ + idx]);
      }
    }
  }
}

// ---------------------------------------------------------------------------
extern "C" void kernel_launch(void* const* d_in, const int* in_sizes, int n_in,
                              void* d_out, int out_size, void* d_ws, size_t ws_size,
                              hipStream_t stream) {
  const float* emb   = (const float*)d_in[0];
  const float* trans = (const float*)d_in[1];
  const int*   rels  = (const int*)d_in[2];
  const int*   order = (const int*)d_in[3];
  const int*   negL  = (const int*)d_in[4];
  const int*   negR  = (const int*)d_in[5];
  float* out = (float*)d_out;
  unsigned short* ws = (unsigned short*)d_ws;  // 4 * B*D * 2B = 16 MB

  prep_kernel<<<B_SZ / 4, 256, 0, stream>>>(emb, trans, rels, out, ws);
  negs_kernel<<<1024, 256, 0, stream>>>(ws, order, negL, negR, out);
}